// Round 4
// baseline (9167.575 us; speedup 1.0000x reference)
//
#include <hip/hip_runtime.h>

typedef unsigned short u16;
typedef __attribute__((ext_vector_type(8))) short short8;
typedef __attribute__((ext_vector_type(4))) float f32x4;

#define DEV __device__ __forceinline__

// B=192, T=64, ACT=16, EMB=1024, STOCH=32, DETER=600, HID=600
// out row stride 1392: [mean_po 0, std_po 32, stoch_po 64, deter 96,
//                       mean_pr 696, std_pr 728, stoch_pr 760, deter 792]
// xd row stride 1280: [x 0..599, deter 600..1199, zero pad 1200..1279]
#define XDS 1280

DEV u16 f2bf(float f) {
  unsigned u = __float_as_uint(f);
  u = (u + 0x7FFFu + ((u >> 16) & 1u)) >> 16;
  return (u16)u;
}
DEV float bf2f(u16 h) { return __uint_as_float(((unsigned)h) << 16); }
DEV float sigf(float x) { return 1.f / (1.f + __expf(-x)); }
DEV float eluf(float x) { return x > 0.f ? x : __expf(x) - 1.f; }
DEV f32x4 MF(short8 a, short8 b, f32x4 c) {
  return __builtin_amdgcn_mfma_f32_16x16x32_bf16(a, b, c, 0, 0, 0);
}

// ---- device-scope grid barrier (all 192 blocks co-resident on 256 CUs) ----
DEV void gbar(unsigned* bar, int nb) {
  __syncthreads();
  if (threadIdx.x == 0) {
    unsigned g = __hip_atomic_load(&bar[1], __ATOMIC_RELAXED, __HIP_MEMORY_SCOPE_AGENT);
    __threadfence();  // release: flush this block's writes (buffer_wbl2 sc1)
    unsigned t = __hip_atomic_fetch_add(&bar[0], 1u, __ATOMIC_ACQ_REL,
                                        __HIP_MEMORY_SCOPE_AGENT);
    if (t == (unsigned)(nb - 1)) {
      __hip_atomic_store(&bar[0], 0u, __ATOMIC_RELAXED, __HIP_MEMORY_SCOPE_AGENT);
      __hip_atomic_fetch_add(&bar[1], 1u, __ATOMIC_RELEASE, __HIP_MEMORY_SCOPE_AGENT);
    } else {
      while (__hip_atomic_load(&bar[1], __ATOMIC_RELAXED, __HIP_MEMORY_SCOPE_AGENT) == g)
        __builtin_amdgcn_s_sleep(1);
    }
    __threadfence();  // acquire: invalidate stale L1/L2 (buffer_inv sc1)
  }
  __syncthreads();
}

// ---------------- f32 -> bf16 with zero row padding (k-major) ----------------
__global__ __launch_bounds__(256) void conv_pad(const float* __restrict__ src,
                                                u16* __restrict__ dst,
                                                int K, int N, int Kpad, int srcRowOff) {
  size_t total = (size_t)Kpad * N;
  for (size_t idx = (size_t)blockIdx.x * 256 + threadIdx.x; idx < total;
       idx += (size_t)gridDim.x * 256) {
    int k = (int)(idx / (size_t)N);
    int n = (int)(idx % (size_t)N);
    dst[idx] = (k < K) ? f2bf(src[(size_t)(k + srcRowOff) * N + n]) : (u16)0;
  }
}

// ---------------- f32 [K0][N0] -> bf16 transposed [Npad][Kpad] ----------------
__global__ __launch_bounds__(256) void conv_T(const float* __restrict__ src,
                                              u16* __restrict__ dst,
                                              int K0, int N0, int Kpad, int Npad) {
  size_t total = (size_t)Npad * Kpad;
  for (size_t idx = (size_t)blockIdx.x * 256 + threadIdx.x; idx < total;
       idx += (size_t)gridDim.x * 256) {
    int n = (int)(idx / (size_t)Kpad);
    int k = (int)(idx % (size_t)Kpad);
    dst[idx] = (k < K0 && n < N0) ? f2bf(src[(size_t)k * N0 + n]) : (u16)0;
  }
}

// ---------------- MFMA 64x64 tile core (LDS-staged, for setup/tail GEMMs) ----
DEV void mfma_tile(const u16 (*As)[72], const u16 (*Bs)[72], int wm, int wn,
                   int lane, f32x4 acc[2][2]) {
#pragma unroll
  for (int s = 0; s < 2; ++s) {
    const int ko = s * 32 + ((lane >> 4) << 3);
    short8 a0 = *reinterpret_cast<const short8*>(&As[wm + (lane & 15)][ko]);
    short8 a1 = *reinterpret_cast<const short8*>(&As[wm + 16 + (lane & 15)][ko]);
    short8 b0 = *reinterpret_cast<const short8*>(&Bs[wn + (lane & 15)][ko]);
    short8 b1 = *reinterpret_cast<const short8*>(&Bs[wn + 16 + (lane & 15)][ko]);
    acc[0][0] = MF(a0, b0, acc[0][0]);
    acc[0][1] = MF(a0, b1, acc[0][1]);
    acc[1][0] = MF(a1, b0, acc[1][0]);
    acc[1][1] = MF(a1, b1, acc[1][1]);
  }
}

// ---------------- generic 64x64-tiled bf16 GEMM (setup/tail) ----------------
// EPI: 1 = +bias, bf16 out ; 2 = +bias, elu, bf16 out
template <int EPI>
__global__ __launch_bounds__(256) void gemm64(
    const u16* __restrict__ A, int lda, const u16* __restrict__ W, int ldw,
    const float* __restrict__ bias, void* __restrict__ Cv, int ldc,
    int Nstore, int N, int K) {
  __shared__ u16 As[64][72];
  __shared__ u16 Bs[64][72];
  const int tid = threadIdx.x, lane = tid & 63, wave = tid >> 6;
  const int wm = (wave & 1) * 32, wn = (wave >> 1) * 32;
  const int bn0 = blockIdx.x * 64, bm0 = blockIdx.y * 64;
  const int am = tid >> 2, ak0 = (tid & 3) * 16;
  const int bk = tid >> 3, bn = (tid & 7) * 8;

  f32x4 acc[2][2] = {};
  for (int k0 = 0; k0 < K; k0 += 64) {
    __syncthreads();
    {
      const u16* src = A + (size_t)(bm0 + am) * lda + k0 + ak0;
      *reinterpret_cast<short8*>(&As[am][ak0]) = *reinterpret_cast<const short8*>(src);
      *reinterpret_cast<short8*>(&As[am][ak0 + 8]) = *reinterpret_cast<const short8*>(src + 8);
    }
    {
      int gn = bn0 + bn;
#pragma unroll
      for (int h = 0; h < 2; ++h) {
        int kk = k0 + bk + h * 32;
        short8 v;
        if (gn + 7 < N) {
          v = *reinterpret_cast<const short8*>(W + (size_t)kk * ldw + gn);
        } else {
          for (int j = 0; j < 8; ++j)
            v[j] = (gn + j < N) ? (short)W[(size_t)kk * ldw + gn + j] : (short)0;
        }
#pragma unroll
        for (int j = 0; j < 8; ++j) Bs[bn + j][bk + h * 32] = (u16)v[j];
      }
    }
    __syncthreads();
    mfma_tile(As, Bs, wm, wn, lane, acc);
  }

#pragma unroll
  for (int r = 0; r < 2; ++r)
#pragma unroll
    for (int c = 0; c < 2; ++c)
#pragma unroll
      for (int i = 0; i < 4; ++i) {
        int grow = bm0 + wm + r * 16 + ((lane >> 4) << 2) + i;
        int gcol = bn0 + wn + c * 16 + (lane & 15);
        if (gcol >= Nstore) continue;
        bool ok = gcol < N;
        float v = acc[r][c][i] + (ok ? bias[gcol] : 0.f);
        if (EPI >= 2) v = eluf(v);
        ((u16*)Cv)[(size_t)grow * ldc + gcol] = ok ? f2bf(v) : (u16)0;
      }
}

// ------- init: x(t=0)=elu(action part), deter=0, pads=0, barrier=0 ----------
__global__ __launch_bounds__(256) void k_init(const float* __restrict__ action,
                                              const float* __restrict__ img1w,
                                              const float* __restrict__ img1b,
                                              float* __restrict__ df32,
                                              u16* __restrict__ xd,
                                              unsigned* __restrict__ bar) {
  __shared__ float act[16];
  int b = blockIdx.x, tid = threadIdx.x;
  if (b == 0 && tid < 8) bar[tid] = 0;
  if (tid < 16) act[tid] = action[(size_t)b * 64 * 16 + tid];  // t = 0
  __syncthreads();
  for (int h = tid; h < 600; h += 256) {
    float s = img1b[h];
#pragma unroll
    for (int a = 0; a < 16; ++a) s += act[a] * img1w[(size_t)(32 + a) * 600 + h];
    xd[(size_t)b * XDS + h] = f2bf(eluf(s));
  }
  for (int j = tid; j < 680; j += 256) xd[(size_t)b * XDS + 600 + j] = 0;
  for (int j = tid; j < 600; j += 256) df32[(size_t)b * 600 + j] = 0.f;
}

// ---------------- batched prior head (tail; N=64 GEMM + dist outputs) --------
__global__ __launch_bounds__(256) void head_prior(
    const u16* __restrict__ A, const u16* __restrict__ W,
    const float* __restrict__ bias64, const float* __restrict__ noise,
    float* __restrict__ out) {
  __shared__ u16 As[64][72];
  __shared__ u16 Bs[64][72];
  __shared__ float sl[64][68];
  const int tid = threadIdx.x, lane = tid & 63, wave = tid >> 6;
  const int wm = (wave & 1) * 32, wn = (wave >> 1) * 32;
  const int bm0 = blockIdx.x * 64;
  const int am = tid >> 2, ak0 = (tid & 3) * 16;
  const int bk = tid >> 3, bn = (tid & 7) * 8;

  f32x4 acc[2][2] = {};
  for (int k0 = 0; k0 < 640; k0 += 64) {
    __syncthreads();
    {
      const u16* src = A + (size_t)(bm0 + am) * 640 + k0 + ak0;
      *reinterpret_cast<short8*>(&As[am][ak0]) = *reinterpret_cast<const short8*>(src);
      *reinterpret_cast<short8*>(&As[am][ak0 + 8]) = *reinterpret_cast<const short8*>(src + 8);
    }
#pragma unroll
    for (int h = 0; h < 2; ++h) {
      int kk = k0 + bk + h * 32;
      short8 v = *reinterpret_cast<const short8*>(W + (size_t)kk * 64 + bn);
#pragma unroll
      for (int j = 0; j < 8; ++j) Bs[bn + j][bk + h * 32] = (u16)v[j];
    }
    __syncthreads();
    mfma_tile(As, Bs, wm, wn, lane, acc);
  }
#pragma unroll
  for (int r = 0; r < 2; ++r)
#pragma unroll
    for (int c = 0; c < 2; ++c)
#pragma unroll
      for (int i = 0; i < 4; ++i) {
        int col = wn + c * 16 + (lane & 15);
        sl[wm + r * 16 + ((lane >> 4) << 2) + i][col] = acc[r][c][i] + bias64[col];
      }
  __syncthreads();
  for (int task = tid; task < 64 * 32; task += 256) {
    int r = task >> 5, j = task & 31;
    size_t orow = (size_t)(bm0 + r);
    size_t base = orow * 1392 + 696;
    float mean = sl[r][j];
    float sd = 2.f * sigf(0.5f * sl[r][32 + j]) + 0.1f;
    float st = mean + sd * noise[orow * 32 + j];
    out[base + j] = mean;
    out[base + 32 + j] = sd;
    out[base + 64 + j] = st;
  }
}

// ---------------- the persistent scan kernel (plain launch + own barrier) ----
struct ScanArgs {
  u16* xd;
  float* df32;
  float* parts;
  const u16* gruwT;   // [1800][1216]
  const float* grub;
  const float* lns;
  const float* lnb;
  u16* dall;          // [12288][640]
  float* out;
  const u16* o1wT;    // [640][640]
  const u16* epre;    // [12288][600]
  const u16* o2wT;    // [64][640]
  const float* obs2b;
  const float* npo;
  const u16* w1pT;    // [640][64]
  const float* img1b;
  const float* action;
  unsigned* bar;
};

__global__ __launch_bounds__(256, 1) void scan64(ScanArgs A) {
  const int bid = blockIdx.x, tid = threadIdx.x;
  const int lane = tid & 63, wave = tid >> 6;
  const int l15 = lane & 15;
  const int koff = (lane >> 4) << 3;   // k-octet offset within 32-k slab
  const int crow = (lane >> 4) << 2;   // C-row base within 16

  __shared__ float pl[1800];
  __shared__ float red[256];
  __shared__ float sl[16][68];
  __shared__ u16 xa[16][72];
  __shared__ u16 hl[16][648];

  for (int t = 0; t < 64; ++t) {
    // ======== Phase A: parts[192][1800] = xd[192][1216] @ gruw ========
    if (bid < 87) {
      const int tm = bid / 29, tn = bid - tm * 29;
      const int bm0 = tm * 64, bn0 = tn * 64;
      const int wm = (wave & 1) * 32, wn = (wave >> 1) * 32;
      const u16* a0p = A.xd + (size_t)(bm0 + wm + l15) * XDS + koff;
      const u16* a1p = a0p + (size_t)16 * XDS;
      const int c0 = bn0 + wn + l15, c1 = c0 + 16;
      const u16* b0p = A.gruwT + (size_t)(c0 < 1800 ? c0 : 0) * 1216 + koff;
      const u16* b1p = A.gruwT + (size_t)(c1 < 1800 ? c1 : 0) * 1216 + koff;
      f32x4 a00{}, a01{}, a10{}, a11{};
#pragma unroll 4
      for (int kk = 0; kk < 1216; kk += 32) {
        short8 a0 = *reinterpret_cast<const short8*>(a0p + kk);
        short8 a1 = *reinterpret_cast<const short8*>(a1p + kk);
        short8 b0 = *reinterpret_cast<const short8*>(b0p + kk);
        short8 b1 = *reinterpret_cast<const short8*>(b1p + kk);
        a00 = MF(a0, b0, a00);
        a01 = MF(a0, b1, a01);
        a10 = MF(a1, b0, a10);
        a11 = MF(a1, b1, a11);
      }
#pragma unroll
      for (int i = 0; i < 4; ++i) {
        float* p0 = A.parts + (size_t)(bm0 + wm + crow + i) * 1800;
        float* p1 = p0 + 16 * 1800;
        if (c0 < 1800) { p0[c0] = a00[i]; p1[c0] = a10[i]; }
        if (c1 < 1800) { p0[c1] = a01[i]; p1[c1] = a11[i]; }
      }
    }
    gbar(A.bar, gridDim.x);

    // ======== Phase B: LN + GRU gates, one batch row per block ========
    {
      const int b = bid;
      float s = 0.f;
#pragma unroll
      for (int it = 0; it < 8; ++it) {
        int i = it * 256 + tid;
        if (i < 1800) {
          float v = A.parts[(size_t)b * 1800 + i] + A.grub[i];
          pl[i] = v;
          s += v;
        }
      }
      red[tid] = s;
      __syncthreads();
      for (int o = 128; o > 0; o >>= 1) {
        if (tid < o) red[tid] += red[tid + o];
        __syncthreads();
      }
      float m = red[0] * (1.f / 1800.f);
      __syncthreads();
      float q = 0.f;
#pragma unroll
      for (int it = 0; it < 8; ++it) {
        int i = it * 256 + tid;
        if (i < 1800) {
          float d = pl[i] - m;
          q += d * d;
        }
      }
      red[tid] = q;
      __syncthreads();
      for (int o = 128; o > 0; o >>= 1) {
        if (tid < o) red[tid] += red[tid + o];
        __syncthreads();
      }
      float rstd = rsqrtf(red[0] * (1.f / 1800.f) + 1e-5f);
      size_t orow = (size_t)b * 64 + t;
#pragma unroll
      for (int it = 0; it < 3; ++it) {
        int j = it * 256 + tid;
        if (j < 600) {
          float p0 = (pl[j] - m) * rstd * A.lns[j] + A.lnb[j];
          float p1 = (pl[600 + j] - m) * rstd * A.lns[600 + j] + A.lnb[600 + j];
          float p2 = (pl[1200 + j] - m) * rstd * A.lns[1200 + j] + A.lnb[1200 + j];
          float r = sigf(p0);
          float cd = tanhf(r * p1);
          float u = sigf(p2 - 1.f);
          float dn = u * cd + (1.f - u) * A.df32[(size_t)b * 600 + j];
          A.df32[(size_t)b * 600 + j] = dn;
          u16 h = f2bf(dn);
          A.xd[(size_t)b * XDS + 600 + j] = h;
          A.dall[orow * 640 + j] = h;
          A.out[orow * 1392 + 96 + j] = dn;
          A.out[orow * 1392 + 792 + j] = dn;
        }
      }
      if (tid < 40) A.dall[orow * 640 + 600 + tid] = 0;
    }
    gbar(A.bar, gridDim.x);

    // ======== Phase CD: obs1 + obs2 head + stoch + next x (12 blocks) ========
    if (bid < 12) {
      const int r0 = bid * 16;
      // obs1: hl = elu(deter @ obs1_w[:600] + epre), cols padded to 640
      {
        const u16* a0p = A.xd + (size_t)(r0 + l15) * XDS + 600 + koff;
#pragma unroll
        for (int ct = 0; ct < 10; ++ct) {
          int n0 = wave * 160 + ct * 16;
          const u16* bp = A.o1wT + (size_t)(n0 + l15) * 640 + koff;
          f32x4 acc{};
#pragma unroll 4
          for (int kk = 0; kk < 640; kk += 32)
            acc = MF(*reinterpret_cast<const short8*>(a0p + kk),
                     *reinterpret_cast<const short8*>(bp + kk), acc);
          int c = n0 + l15;
#pragma unroll
          for (int i = 0; i < 4; ++i) {
            u16 o = 0;
            if (c < 600)
              o = f2bf(eluf(acc[i] +
                            bf2f(A.epre[((size_t)(r0 + crow + i) * 64 + t) * 600 + c])));
            hl[crow + i][c] = o;
          }
        }
      }
      __syncthreads();
      // obs2: sl[16][64] = hl @ obs2_w + obs2_b
      {
        int n0 = wave * 16;
        const u16* bp = A.o2wT + (size_t)(n0 + l15) * 640 + koff;
        f32x4 acc{};
#pragma unroll 4
        for (int kk = 0; kk < 640; kk += 32)
          acc = MF(*reinterpret_cast<const short8*>(&hl[l15][koff + kk]),
                   *reinterpret_cast<const short8*>(bp + kk), acc);
#pragma unroll
        for (int i = 0; i < 4; ++i)
          sl[crow + i][n0 + l15] = acc[i] + A.obs2b[n0 + l15];
      }
      __syncthreads();
      // head outputs + stoch + xa
      for (int task = tid; task < 512; task += 256) {
        int r = task >> 5, j = task & 31;
        size_t orow = (size_t)(r0 + r) * 64 + t;
        float mean = sl[r][j];
        float sd = 2.f * sigf(0.5f * sl[r][32 + j]) + 0.1f;
        float st = mean + sd * A.npo[orow * 32 + j];
        float* ob = A.out + orow * 1392;
        ob[j] = mean;
        ob[32 + j] = sd;
        ob[64 + j] = st;
        xa[r][j] = f2bf(st);
      }
      {
        int r = tid >> 4, a2 = tid & 15;
        xa[r][32 + a2] =
            (t < 63) ? f2bf(A.action[((size_t)(r0 + r) * 64 + t + 1) * 16 + a2]) : (u16)0;
        xa[r][48 + a2] = 0;
      }
      __syncthreads();
      // next x = elu([stoch, action_{t+1}] @ img1_w + img1_b)
      if (t < 63) {
        for (int g = wave; g < 40; g += 4) {
          const u16* bp = A.w1pT + (size_t)(g * 16 + l15) * 64 + koff;
          f32x4 ax{};
          ax = MF(*reinterpret_cast<const short8*>(&xa[l15][koff]),
                  *reinterpret_cast<const short8*>(bp), ax);
          ax = MF(*reinterpret_cast<const short8*>(&xa[l15][32 + koff]),
                  *reinterpret_cast<const short8*>(bp + 32), ax);
          int c = g * 16 + l15;
          if (c < 600) {
            float bi = A.img1b[c];
#pragma unroll
            for (int i = 0; i < 4; ++i)
              A.xd[(size_t)(r0 + crow + i) * XDS + c] = f2bf(eluf(ax[i] + bi));
          }
        }
      }
      __syncthreads();  // protect sl/xa/hl before next iteration
    }
    gbar(A.bar, gridDim.x);
  }
}

// ---------------- launch ----------------
extern "C" void kernel_launch(void* const* d_in, const int* in_sizes, int n_in,
                              void* d_out, int out_size, void* d_ws, size_t ws_size,
                              hipStream_t stream) {
  (void)in_sizes; (void)n_in; (void)out_size; (void)ws_size;
  const float* action = (const float*)d_in[0];
  const float* embed = (const float*)d_in[1];
  const float* npr = (const float*)d_in[2];
  const float* npo = (const float*)d_in[3];
  const float* img1w = (const float*)d_in[4];
  const float* img1b = (const float*)d_in[5];
  const float* gruw = (const float*)d_in[6];
  const float* grub = (const float*)d_in[7];
  const float* lns = (const float*)d_in[8];
  const float* lnb = (const float*)d_in[9];
  const float* img2w = (const float*)d_in[10];
  const float* img2b = (const float*)d_in[11];
  const float* img3w = (const float*)d_in[12];
  const float* img3b = (const float*)d_in[13];
  const float* obs1w = (const float*)d_in[14];
  const float* obs1b = (const float*)d_in[15];
  const float* obs2w = (const float*)d_in[16];
  const float* obs2b = (const float*)d_in[17];
  float* out = (float*)d_out;
  char* ws = (char*)d_ws;

  size_t off = 0;
  auto alloc = [&](size_t bytes) {
    size_t o = off;
    off += (bytes + 255) & ~(size_t)255;
    return o;
  };
  size_t o_bar = alloc(256);
  size_t o_embed = alloc(12288ull * 1024 * 2);  // reused as dall (12288x640)
  size_t o_epre = alloc(12288ull * 600 * 2);    // reused (with o_wemb) as h_img
  size_t o_wemb = alloc(1024ull * 600 * 2);
  size_t o_gruwT = alloc(1800ull * 1216 * 2);
  size_t o_o1wT = alloc(640ull * 640 * 2);
  size_t o_o2wT = alloc(64ull * 640 * 2);
  size_t o_w1pT = alloc(640ull * 64 * 2);
  size_t o_i2w = alloc(640ull * 600 * 2);
  size_t o_i3w = alloc(640ull * 64 * 2);
  size_t o_xd = alloc(192ull * XDS * 2);
  size_t o_parts = alloc(192ull * 1800 * 4);
  size_t o_df32 = alloc(192ull * 600 * 4);

  unsigned* bar = (unsigned*)(ws + o_bar);
  u16* embed_bf = (u16*)(ws + o_embed);
  u16* dall = (u16*)(ws + o_embed);
  u16* epre = (u16*)(ws + o_epre);
  u16* himg = (u16*)(ws + o_epre);
  u16* wemb = (u16*)(ws + o_wemb);
  u16* gruwT = (u16*)(ws + o_gruwT);
  u16* o1wT = (u16*)(ws + o_o1wT);
  u16* o2wT = (u16*)(ws + o_o2wT);
  u16* w1pT = (u16*)(ws + o_w1pT);
  u16* i2wb = (u16*)(ws + o_i2w);
  u16* i3wb = (u16*)(ws + o_i3w);
  u16* xd = (u16*)(ws + o_xd);
  float* parts = (float*)(ws + o_parts);
  float* df32 = (float*)(ws + o_df32);

  auto cgr = [](size_t total) {
    size_t g = (total + 255) / 256;
    return (unsigned)(g > 4096 ? 4096 : g);
  };

  // setup conversions
  conv_pad<<<cgr(12288ull * 1024), 256, 0, stream>>>(embed, embed_bf, 12288, 1024, 12288, 0);
  conv_pad<<<cgr(1024ull * 600), 256, 0, stream>>>(obs1w, wemb, 1024, 600, 1024, 600);
  conv_pad<<<cgr(640ull * 600), 256, 0, stream>>>(img2w, i2wb, 600, 600, 640, 0);
  conv_pad<<<cgr(640ull * 64), 256, 0, stream>>>(img3w, i3wb, 600, 64, 640, 0);
  conv_T<<<cgr(1800ull * 1216), 256, 0, stream>>>(gruw, gruwT, 1200, 1800, 1216, 1800);
  conv_T<<<cgr(640ull * 640), 256, 0, stream>>>(obs1w, o1wT, 600, 600, 640, 640);
  conv_T<<<cgr(64ull * 640), 256, 0, stream>>>(obs2w, o2wT, 600, 64, 640, 64);
  conv_T<<<cgr(640ull * 64), 256, 0, stream>>>(img1w, w1pT, 48, 600, 64, 640);

  k_init<<<192, 256, 0, stream>>>(action, img1w, img1b, df32, xd, bar);

  // epre[b*64+t][h] = embed @ obs1_w[600:,:] + obs1_b   (bf16 out)
  gemm64<1><<<dim3(10, 192), 256, 0, stream>>>(embed_bf, 1024, wemb, 600, obs1b,
                                               epre, 600, 600, 600, 1024);

  // the whole 64-step scan in one plain-launch kernel with a device barrier
  ScanArgs sa;
  sa.xd = xd; sa.df32 = df32; sa.parts = parts;
  sa.gruwT = gruwT; sa.grub = grub; sa.lns = lns; sa.lnb = lnb;
  sa.dall = dall; sa.out = out;
  sa.o1wT = o1wT; sa.epre = epre;
  sa.o2wT = o2wT; sa.obs2b = obs2b; sa.npo = npo;
  sa.w1pT = w1pT; sa.img1b = img1b; sa.action = action;
  sa.bar = bar;
  scan64<<<192, 256, 0, stream>>>(sa);

  // batched prior: h_img = elu(deter_all @ img2_w + img2_b), then img3 head
  gemm64<2><<<dim3(10, 192), 256, 0, stream>>>(dall, 640, i2wb, 600, img2b,
                                               himg, 640, 640, 600, 640);
  head_prior<<<192, 256, 0, stream>>>(himg, i3wb, img3b, npr, out);
}

// Round 5
// 5535.785 us; speedup vs baseline: 1.6561x; 1.6561x over previous
//
#include <hip/hip_runtime.h>

typedef unsigned short u16;
typedef __attribute__((ext_vector_type(8))) short short8;
typedef __attribute__((ext_vector_type(4))) float f32x4;

#define DEV __device__ __forceinline__

// B=192, T=64, ACT=16, EMB=1024, STOCH=32, DETER=600, HID=600
// out row stride 1392: [mean_po 0, std_po 32, stoch_po 64, deter 96,
//                       mean_pr 696, std_pr 728, stoch_pr 760, deter 792]
// xd row stride 1280: [x 0..599, deter 600..1199, zero pad 1200..1279]
#define XDS 1280

DEV u16 f2bf(float f) {
  unsigned u = __float_as_uint(f);
  u = (u + 0x7FFFu + ((u >> 16) & 1u)) >> 16;
  return (u16)u;
}
DEV float bf2f(u16 h) { return __uint_as_float(((unsigned)h) << 16); }
DEV float sigf(float x) { return 1.f / (1.f + __expf(-x)); }
DEV float eluf(float x) { return x > 0.f ? x : __expf(x) - 1.f; }
DEV f32x4 MF(short8 a, short8 b, f32x4 c) {
  return __builtin_amdgcn_mfma_f32_16x16x32_bf16(a, b, c, 0, 0, 0);
}

// ---- agent-coherent (sc1, MALL-served) access helpers: bypass L1/L2 so no
// ---- fence / L2 invalidate is ever needed; weights stay warm in L2. ----
DEV unsigned long long ald64(const void* p) {
  return __hip_atomic_load((const unsigned long long*)p, __ATOMIC_RELAXED,
                           __HIP_MEMORY_SCOPE_AGENT);
}
DEV short8 ald16B(const u16* p) {
  union { unsigned long long u[2]; short8 v; } x;
  x.u[0] = ald64(p);
  x.u[1] = ald64(p + 4);
  return x.v;
}
DEV void ast32(void* p, unsigned v) {
  __hip_atomic_store((unsigned*)p, v, __ATOMIC_RELAXED, __HIP_MEMORY_SCOPE_AGENT);
}
DEV void astf(float* p, float v) { ast32(p, __float_as_uint(v)); }
DEV float aldf(const float* p) {
  return __uint_as_float(
      __hip_atomic_load((const unsigned*)p, __ATOMIC_RELAXED, __HIP_MEMORY_SCOPE_AGENT));
}

// ---- fence-free grid barrier: cross-block data is all sc1 (write-through),
// ---- __syncthreads drains vmcnt(0) => stores globally visible at arrival. ----
DEV void gbar(unsigned* bar, int nb) {
  __syncthreads();
  if (threadIdx.x == 0) {
    unsigned g = __hip_atomic_load(&bar[1], __ATOMIC_RELAXED, __HIP_MEMORY_SCOPE_AGENT);
    unsigned t = __hip_atomic_fetch_add(&bar[0], 1u, __ATOMIC_RELAXED,
                                        __HIP_MEMORY_SCOPE_AGENT);
    if (t == (unsigned)(nb - 1)) {
      __hip_atomic_store(&bar[0], 0u, __ATOMIC_RELAXED, __HIP_MEMORY_SCOPE_AGENT);
      __hip_atomic_fetch_add(&bar[1], 1u, __ATOMIC_RELAXED, __HIP_MEMORY_SCOPE_AGENT);
    } else {
      while (__hip_atomic_load(&bar[1], __ATOMIC_RELAXED, __HIP_MEMORY_SCOPE_AGENT) == g)
        __builtin_amdgcn_s_sleep(1);
    }
  }
  __syncthreads();
}

// ---------------- f32 -> bf16 with zero row padding (k-major) ----------------
__global__ __launch_bounds__(256) void conv_pad(const float* __restrict__ src,
                                                u16* __restrict__ dst,
                                                int K, int N, int Kpad, int srcRowOff) {
  size_t total = (size_t)Kpad * N;
  for (size_t idx = (size_t)blockIdx.x * 256 + threadIdx.x; idx < total;
       idx += (size_t)gridDim.x * 256) {
    int k = (int)(idx / (size_t)N);
    int n = (int)(idx % (size_t)N);
    dst[idx] = (k < K) ? f2bf(src[(size_t)(k + srcRowOff) * N + n]) : (u16)0;
  }
}

// ---------------- f32 [K0][N0] -> bf16 transposed [Npad][Kpad] ----------------
__global__ __launch_bounds__(256) void conv_T(const float* __restrict__ src,
                                              u16* __restrict__ dst,
                                              int K0, int N0, int Kpad, int Npad) {
  size_t total = (size_t)Npad * Kpad;
  for (size_t idx = (size_t)blockIdx.x * 256 + threadIdx.x; idx < total;
       idx += (size_t)gridDim.x * 256) {
    int n = (int)(idx / (size_t)Kpad);
    int k = (int)(idx % (size_t)Kpad);
    dst[idx] = (k < K0 && n < N0) ? f2bf(src[(size_t)k * N0 + n]) : (u16)0;
  }
}

// ---------------- MFMA 64x64 tile core (LDS-staged, for setup/tail GEMMs) ----
DEV void mfma_tile(const u16 (*As)[72], const u16 (*Bs)[72], int wm, int wn,
                   int lane, f32x4 acc[2][2]) {
#pragma unroll
  for (int s = 0; s < 2; ++s) {
    const int ko = s * 32 + ((lane >> 4) << 3);
    short8 a0 = *reinterpret_cast<const short8*>(&As[wm + (lane & 15)][ko]);
    short8 a1 = *reinterpret_cast<const short8*>(&As[wm + 16 + (lane & 15)][ko]);
    short8 b0 = *reinterpret_cast<const short8*>(&Bs[wn + (lane & 15)][ko]);
    short8 b1 = *reinterpret_cast<const short8*>(&Bs[wn + 16 + (lane & 15)][ko]);
    acc[0][0] = MF(a0, b0, acc[0][0]);
    acc[0][1] = MF(a0, b1, acc[0][1]);
    acc[1][0] = MF(a1, b0, acc[1][0]);
    acc[1][1] = MF(a1, b1, acc[1][1]);
  }
}

// ---------------- generic 64x64-tiled bf16 GEMM (setup/tail) ----------------
// EPI: 2 = +bias, elu, bf16 out ; 4 = +bias, bf16 out, epre-permuted store
template <int EPI>
__global__ __launch_bounds__(256) void gemm64(
    const u16* __restrict__ A, int lda, const u16* __restrict__ W, int ldw,
    const float* __restrict__ bias, void* __restrict__ Cv, int ldc,
    int Nstore, int N, int K) {
  __shared__ u16 As[64][72];
  __shared__ u16 Bs[64][72];
  const int tid = threadIdx.x, lane = tid & 63, wave = tid >> 6;
  const int wm = (wave & 1) * 32, wn = (wave >> 1) * 32;
  const int bn0 = blockIdx.x * 64, bm0 = blockIdx.y * 64;
  const int am = tid >> 2, ak0 = (tid & 3) * 16;
  const int bk = tid >> 3, bn = (tid & 7) * 8;

  f32x4 acc[2][2] = {};
  for (int k0 = 0; k0 < K; k0 += 64) {
    __syncthreads();
    {
      const u16* src = A + (size_t)(bm0 + am) * lda + k0 + ak0;
      *reinterpret_cast<short8*>(&As[am][ak0]) = *reinterpret_cast<const short8*>(src);
      *reinterpret_cast<short8*>(&As[am][ak0 + 8]) = *reinterpret_cast<const short8*>(src + 8);
    }
    {
      int gn = bn0 + bn;
#pragma unroll
      for (int h = 0; h < 2; ++h) {
        int kk = k0 + bk + h * 32;
        short8 v;
        if (gn + 7 < N) {
          v = *reinterpret_cast<const short8*>(W + (size_t)kk * ldw + gn);
        } else {
          for (int j = 0; j < 8; ++j)
            v[j] = (gn + j < N) ? (short)W[(size_t)kk * ldw + gn + j] : (short)0;
        }
#pragma unroll
        for (int j = 0; j < 8; ++j) Bs[bn + j][bk + h * 32] = (u16)v[j];
      }
    }
    __syncthreads();
    mfma_tile(As, Bs, wm, wn, lane, acc);
  }

#pragma unroll
  for (int r = 0; r < 2; ++r)
#pragma unroll
    for (int c = 0; c < 2; ++c)
#pragma unroll
      for (int i = 0; i < 4; ++i) {
        int grow = bm0 + wm + r * 16 + ((lane >> 4) << 2) + i;
        int gcol = bn0 + wn + c * 16 + (lane & 15);
        if (gcol >= Nstore) continue;
        bool ok = gcol < N;
        float v = acc[r][c][i] + (ok ? bias[gcol] : 0.f);
        if (EPI == 2) {
          v = eluf(v);
          ((u16*)Cv)[(size_t)grow * ldc + gcol] = ok ? f2bf(v) : (u16)0;
        } else {  // EPI 4: epre[t][b][600] layout
          size_t row2 = (size_t)(grow & 63) * 192 + (size_t)(grow >> 6);
          ((u16*)Cv)[row2 * 600 + gcol] = f2bf(v);
        }
      }
}

// ------- init: x(t=0)=elu(action part), deter=0, pads=0, barrier=0 ----------
__global__ __launch_bounds__(256) void k_init(const float* __restrict__ action,
                                              const float* __restrict__ img1w,
                                              const float* __restrict__ img1b,
                                              u16* __restrict__ xd,
                                              unsigned* __restrict__ bar) {
  __shared__ float act[16];
  int b = blockIdx.x, tid = threadIdx.x;
  if (b == 0 && tid < 8) bar[tid] = 0;
  if (tid < 16) act[tid] = action[(size_t)b * 64 * 16 + tid];  // t = 0
  __syncthreads();
  for (int h = tid; h < 600; h += 256) {
    float s = img1b[h];
#pragma unroll
    for (int a = 0; a < 16; ++a) s += act[a] * img1w[(size_t)(32 + a) * 600 + h];
    xd[(size_t)b * XDS + h] = f2bf(eluf(s));
  }
  for (int j = tid; j < 680; j += 256) xd[(size_t)b * XDS + 600 + j] = 0;
}

// ---------------- batched prior head (tail; N=64 GEMM + dist outputs) --------
__global__ __launch_bounds__(256) void head_prior(
    const u16* __restrict__ A, const u16* __restrict__ W,
    const float* __restrict__ bias64, const float* __restrict__ noise,
    float* __restrict__ out) {
  __shared__ u16 As[64][72];
  __shared__ u16 Bs[64][72];
  __shared__ float sl[64][68];
  const int tid = threadIdx.x, lane = tid & 63, wave = tid >> 6;
  const int wm = (wave & 1) * 32, wn = (wave >> 1) * 32;
  const int bm0 = blockIdx.x * 64;
  const int am = tid >> 2, ak0 = (tid & 3) * 16;
  const int bk = tid >> 3, bn = (tid & 7) * 8;

  f32x4 acc[2][2] = {};
  for (int k0 = 0; k0 < 640; k0 += 64) {
    __syncthreads();
    {
      const u16* src = A + (size_t)(bm0 + am) * 640 + k0 + ak0;
      *reinterpret_cast<short8*>(&As[am][ak0]) = *reinterpret_cast<const short8*>(src);
      *reinterpret_cast<short8*>(&As[am][ak0 + 8]) = *reinterpret_cast<const short8*>(src + 8);
    }
#pragma unroll
    for (int h = 0; h < 2; ++h) {
      int kk = k0 + bk + h * 32;
      short8 v = *reinterpret_cast<const short8*>(W + (size_t)kk * 64 + bn);
#pragma unroll
      for (int j = 0; j < 8; ++j) Bs[bn + j][bk + h * 32] = (u16)v[j];
    }
    __syncthreads();
    mfma_tile(As, Bs, wm, wn, lane, acc);
  }
#pragma unroll
  for (int r = 0; r < 2; ++r)
#pragma unroll
    for (int c = 0; c < 2; ++c)
#pragma unroll
      for (int i = 0; i < 4; ++i) {
        int col = wn + c * 16 + (lane & 15);
        sl[wm + r * 16 + ((lane >> 4) << 2) + i][col] = acc[r][c][i] + bias64[col];
      }
  __syncthreads();
  for (int task = tid; task < 64 * 32; task += 256) {
    int r = task >> 5, j = task & 31;
    size_t orow = (size_t)(bm0 + r);
    size_t base = orow * 1392 + 696;
    float mean = sl[r][j];
    float sd = 2.f * sigf(0.5f * sl[r][32 + j]) + 0.1f;
    float st = mean + sd * noise[orow * 32 + j];
    out[base + j] = mean;
    out[base + 32 + j] = sd;
    out[base + 64 + j] = st;
  }
}

// ---------------- the persistent scan kernel (plain launch + own barrier) ----
struct ScanArgs {
  u16* xd;            // [192][XDS] carry (sc1)
  float* parts;       // [192][1800] (sc1)
  const u16* gruwT;   // [1800][1216] (cached)
  const float* grub;
  const float* lns;
  const float* lnb;
  u16* dall;          // [12288][640] (plain; read after kernel end)
  float* out;
  const u16* o1wT;    // [640][640]
  const u16* epre;    // [64][192][600] (t-major)
  u16* hobs;          // [192][640] (sc1)
  const u16* o2wT;    // [64][640]
  const float* obs2b;
  const float* npo;
  const u16* w1pT;    // [640][64]
  const float* img1b;
  const float* action;
  unsigned* bar;
};

__global__ __launch_bounds__(256, 1) void scan64(ScanArgs A) {
  const int bid = blockIdx.x, tid = threadIdx.x;
  const int lane = tid & 63, wave = tid >> 6;
  const int l15 = lane & 15;
  const int koff = (lane >> 4) << 3;   // k-octet offset within 32-k slab
  const int crow = (lane >> 4) << 2;   // C-row base within 16

  __shared__ float pl[1800];
  __shared__ float red[256];
  __shared__ float dsh[600];   // per-block deter carry (block b <-> batch row b)
  __shared__ float sl[16][68];
  __shared__ u16 xa[16][72];

  for (int j = tid; j < 600; j += 256) dsh[j] = 0.f;

  for (int t = 0; t < 64; ++t) {
    // ======== Phase A: parts[192][1800] = xd[192][1216] @ gruw ========
    if (bid < 87) {
      const int tm = bid / 29, tn = bid - tm * 29;
      const int bm0 = tm * 64, bn0 = tn * 64;
      const int wm = (wave & 1) * 32, wn = (wave >> 1) * 32;
      const u16* a0p = A.xd + (size_t)(bm0 + wm + l15) * XDS + koff;
      const u16* a1p = a0p + (size_t)16 * XDS;
      const int c0 = bn0 + wn + l15, c1 = c0 + 16;
      const u16* b0p = A.gruwT + (size_t)(c0 < 1800 ? c0 : 0) * 1216 + koff;
      const u16* b1p = A.gruwT + (size_t)(c1 < 1800 ? c1 : 0) * 1216 + koff;
      f32x4 a00{}, a01{}, a10{}, a11{};
#pragma unroll 4
      for (int kk = 0; kk < 1216; kk += 32) {
        short8 a0 = ald16B(a0p + kk);
        short8 a1 = ald16B(a1p + kk);
        short8 b0 = *reinterpret_cast<const short8*>(b0p + kk);
        short8 b1 = *reinterpret_cast<const short8*>(b1p + kk);
        a00 = MF(a0, b0, a00);
        a01 = MF(a0, b1, a01);
        a10 = MF(a1, b0, a10);
        a11 = MF(a1, b1, a11);
      }
#pragma unroll
      for (int i = 0; i < 4; ++i) {
        float* p0 = A.parts + (size_t)(bm0 + wm + crow + i) * 1800;
        float* p1 = p0 + 16 * 1800;
        if (c0 < 1800) { astf(&p0[c0], a00[i]); astf(&p1[c0], a10[i]); }
        if (c1 < 1800) { astf(&p0[c1], a01[i]); astf(&p1[c1], a11[i]); }
      }
    }
    gbar(A.bar, gridDim.x);

    // ======== Phase B: LN + GRU gates, one batch row per block ========
    {
      const int b = bid;
      float s = 0.f;
#pragma unroll
      for (int it = 0; it < 8; ++it) {
        int i = it * 256 + tid;
        if (i < 1800) {
          float v = aldf(&A.parts[(size_t)b * 1800 + i]) + A.grub[i];
          pl[i] = v;
          s += v;
        }
      }
      red[tid] = s;
      __syncthreads();
      for (int o = 128; o > 0; o >>= 1) {
        if (tid < o) red[tid] += red[tid + o];
        __syncthreads();
      }
      float m = red[0] * (1.f / 1800.f);
      __syncthreads();
      float q = 0.f;
#pragma unroll
      for (int it = 0; it < 8; ++it) {
        int i = it * 256 + tid;
        if (i < 1800) {
          float d = pl[i] - m;
          q += d * d;
        }
      }
      red[tid] = q;
      __syncthreads();
      for (int o = 128; o > 0; o >>= 1) {
        if (tid < o) red[tid] += red[tid + o];
        __syncthreads();
      }
      float rstd = rsqrtf(red[0] * (1.f / 1800.f) + 1e-5f);
      size_t orow = (size_t)b * 64 + t;
#pragma unroll
      for (int it = 0; it < 3; ++it) {
        int j = it * 256 + tid;
        if (j < 600) {
          float p0 = (pl[j] - m) * rstd * A.lns[j] + A.lnb[j];
          float p1 = (pl[600 + j] - m) * rstd * A.lns[600 + j] + A.lnb[600 + j];
          float p2 = (pl[1200 + j] - m) * rstd * A.lns[1200 + j] + A.lnb[1200 + j];
          float r = sigf(p0);
          float cd = tanhf(r * p1);
          float u = sigf(p2 - 1.f);
          float dn = u * cd + (1.f - u) * dsh[j];
          dsh[j] = dn;
          A.out[orow * 1392 + 96 + j] = dn;
          A.out[orow * 1392 + 792 + j] = dn;
        }
      }
      __syncthreads();
      // pack deter to bf16 pairs: sc1 into xd, plain into dall
      for (int it = 0; it < 2; ++it) {
        int idx = it * 256 + tid;
        if (idx < 300) {
          int j = idx * 2;
          unsigned pk = (unsigned)f2bf(dsh[j]) | ((unsigned)f2bf(dsh[j + 1]) << 16);
          ast32(A.xd + (size_t)b * XDS + 600 + j, pk);
          *reinterpret_cast<unsigned*>(A.dall + orow * 640 + j) = pk;
        }
      }
      if (tid < 20) *reinterpret_cast<unsigned*>(A.dall + orow * 640 + 600 + tid * 2) = 0;
    }
    gbar(A.bar, gridDim.x);

    // ======== Phase C: hobs = elu(deter @ obs1_w[:600] + epre)  (120 blocks) ==
    if (bid < 120) {
      const int rg = bid / 10, cg = bid - rg * 10;
      const int r0 = rg * 16;
      const int c = cg * 64 + wave * 16 + l15;  // < 640
      const u16* ap = A.xd + (size_t)(r0 + l15) * XDS + 600 + koff;
      const u16* bp = A.o1wT + (size_t)c * 640 + koff;
      f32x4 acc{};
#pragma unroll 4
      for (int kk = 0; kk < 640; kk += 32)
        acc = MF(ald16B(ap + kk), *reinterpret_cast<const short8*>(bp + kk), acc);
#pragma unroll
      for (int i = 0; i < 4; ++i) {
        int r = r0 + crow + i;
        unsigned hv = 0;
        if (c < 600)
          hv = f2bf(eluf(acc[i] + bf2f(A.epre[((size_t)t * 192 + r) * 600 + c])));
        unsigned ov = (unsigned)__shfl_xor((int)hv, 1);
        if (!(l15 & 1))
          ast32(A.hobs + (size_t)r * 640 + c, hv | (ov << 16));
      }
    }
    gbar(A.bar, gridDim.x);

    // ======== Phase D: obs2 head + stoch + next x (12 blocks, 16 rows) ========
    if (bid < 12) {
      const int r0 = bid * 16;
      const int n0 = wave * 16;
      {
        const u16* ap = A.hobs + (size_t)(r0 + l15) * 640 + koff;
        const u16* bp = A.o2wT + (size_t)(n0 + l15) * 640 + koff;
        f32x4 acc{};
#pragma unroll 4
        for (int kk = 0; kk < 640; kk += 32)
          acc = MF(ald16B(ap + kk), *reinterpret_cast<const short8*>(bp + kk), acc);
#pragma unroll
        for (int i = 0; i < 4; ++i)
          sl[crow + i][n0 + l15] = acc[i] + A.obs2b[n0 + l15];
      }
      __syncthreads();
      for (int task = tid; task < 512; task += 256) {
        int r = task >> 5, j = task & 31;
        size_t orow = (size_t)(r0 + r) * 64 + t;
        float mean = sl[r][j];
        float sd = 2.f * sigf(0.5f * sl[r][32 + j]) + 0.1f;
        float st = mean + sd * A.npo[orow * 32 + j];
        float* ob = A.out + orow * 1392;
        ob[j] = mean;
        ob[32 + j] = sd;
        ob[64 + j] = st;
        xa[r][j] = f2bf(st);
      }
      {
        int r = tid >> 4, a2 = tid & 15;
        xa[r][32 + a2] =
            (t < 63) ? f2bf(A.action[((size_t)(r0 + r) * 64 + t + 1) * 16 + a2]) : (u16)0;
        xa[r][48 + a2] = 0;
      }
      __syncthreads();
      // next x = elu([stoch, action_{t+1}] @ img1_w + img1_b) -> xd (sc1)
      if (t < 63) {
        for (int g = wave; g < 38; g += 4) {
          const u16* bp = A.w1pT + (size_t)(g * 16 + l15) * 64 + koff;
          f32x4 ax{};
          ax = MF(*reinterpret_cast<const short8*>(&xa[l15][koff]),
                  *reinterpret_cast<const short8*>(bp), ax);
          ax = MF(*reinterpret_cast<const short8*>(&xa[l15][32 + koff]),
                  *reinterpret_cast<const short8*>(bp + 32), ax);
          int c = g * 16 + l15;
          if (c < 600) {
            float bi = A.img1b[c];
#pragma unroll
            for (int i = 0; i < 4; ++i) {
              unsigned hv = f2bf(eluf(ax[i] + bi));
              unsigned ov = (unsigned)__shfl_xor((int)hv, 1);
              if (!(l15 & 1))
                ast32(A.xd + (size_t)(r0 + crow + i) * XDS + c, hv | (ov << 16));
            }
          }
        }
      }
      __syncthreads();  // protect sl/xa before next iteration
    }
    gbar(A.bar, gridDim.x);
  }
}

// ---------------- launch ----------------
extern "C" void kernel_launch(void* const* d_in, const int* in_sizes, int n_in,
                              void* d_out, int out_size, void* d_ws, size_t ws_size,
                              hipStream_t stream) {
  (void)in_sizes; (void)n_in; (void)out_size; (void)ws_size;
  const float* action = (const float*)d_in[0];
  const float* embed = (const float*)d_in[1];
  const float* npr = (const float*)d_in[2];
  const float* npo = (const float*)d_in[3];
  const float* img1w = (const float*)d_in[4];
  const float* img1b = (const float*)d_in[5];
  const float* gruw = (const float*)d_in[6];
  const float* grub = (const float*)d_in[7];
  const float* lns = (const float*)d_in[8];
  const float* lnb = (const float*)d_in[9];
  const float* img2w = (const float*)d_in[10];
  const float* img2b = (const float*)d_in[11];
  const float* img3w = (const float*)d_in[12];
  const float* img3b = (const float*)d_in[13];
  const float* obs1w = (const float*)d_in[14];
  const float* obs1b = (const float*)d_in[15];
  const float* obs2w = (const float*)d_in[16];
  const float* obs2b = (const float*)d_in[17];
  float* out = (float*)d_out;
  char* ws = (char*)d_ws;

  size_t off = 0;
  auto alloc = [&](size_t bytes) {
    size_t o = off;
    off += (bytes + 255) & ~(size_t)255;
    return o;
  };
  size_t o_bar = alloc(256);
  size_t o_embed = alloc(12288ull * 1024 * 2);  // reused as dall (12288x640)
  size_t o_epre = alloc(12288ull * 600 * 2);    // reused (with o_wemb) as h_img
  size_t o_wemb = alloc(1024ull * 600 * 2);
  size_t o_gruwT = alloc(1800ull * 1216 * 2);
  size_t o_o1wT = alloc(640ull * 640 * 2);
  size_t o_o2wT = alloc(64ull * 640 * 2);
  size_t o_w1pT = alloc(640ull * 64 * 2);
  size_t o_i2w = alloc(640ull * 600 * 2);
  size_t o_i3w = alloc(640ull * 64 * 2);
  size_t o_xd = alloc(192ull * XDS * 2);
  size_t o_parts = alloc(192ull * 1800 * 4);
  size_t o_hobs = alloc(192ull * 640 * 2);

  unsigned* bar = (unsigned*)(ws + o_bar);
  u16* embed_bf = (u16*)(ws + o_embed);
  u16* dall = (u16*)(ws + o_embed);
  u16* epre = (u16*)(ws + o_epre);
  u16* himg = (u16*)(ws + o_epre);
  u16* wemb = (u16*)(ws + o_wemb);
  u16* gruwT = (u16*)(ws + o_gruwT);
  u16* o1wT = (u16*)(ws + o_o1wT);
  u16* o2wT = (u16*)(ws + o_o2wT);
  u16* w1pT = (u16*)(ws + o_w1pT);
  u16* i2wb = (u16*)(ws + o_i2w);
  u16* i3wb = (u16*)(ws + o_i3w);
  u16* xd = (u16*)(ws + o_xd);
  float* parts = (float*)(ws + o_parts);
  u16* hobs = (u16*)(ws + o_hobs);

  auto cgr = [](size_t total) {
    size_t g = (total + 255) / 256;
    return (unsigned)(g > 4096 ? 4096 : g);
  };

  // setup conversions
  conv_pad<<<cgr(12288ull * 1024), 256, 0, stream>>>(embed, embed_bf, 12288, 1024, 12288, 0);
  conv_pad<<<cgr(1024ull * 600), 256, 0, stream>>>(obs1w, wemb, 1024, 600, 1024, 600);
  conv_pad<<<cgr(640ull * 600), 256, 0, stream>>>(img2w, i2wb, 600, 600, 640, 0);
  conv_pad<<<cgr(640ull * 64), 256, 0, stream>>>(img3w, i3wb, 600, 64, 640, 0);
  conv_T<<<cgr(1800ull * 1216), 256, 0, stream>>>(gruw, gruwT, 1200, 1800, 1216, 1800);
  conv_T<<<cgr(640ull * 640), 256, 0, stream>>>(obs1w, o1wT, 600, 600, 640, 640);
  conv_T<<<cgr(64ull * 640), 256, 0, stream>>>(obs2w, o2wT, 600, 64, 640, 64);
  conv_T<<<cgr(640ull * 64), 256, 0, stream>>>(img1w, w1pT, 48, 600, 64, 640);

  k_init<<<192, 256, 0, stream>>>(action, img1w, img1b, xd, bar);

  // epre[t][b][600] = embed @ obs1_w[600:,:] + obs1_b   (bf16, t-major)
  gemm64<4><<<dim3(10, 192), 256, 0, stream>>>(embed_bf, 1024, wemb, 600, obs1b,
                                               epre, 600, 600, 600, 1024);

  // the whole 64-step scan in one plain-launch kernel with a fence-free barrier
  ScanArgs sa;
  sa.xd = xd; sa.parts = parts;
  sa.gruwT = gruwT; sa.grub = grub; sa.lns = lns; sa.lnb = lnb;
  sa.dall = dall; sa.out = out;
  sa.o1wT = o1wT; sa.epre = epre; sa.hobs = hobs;
  sa.o2wT = o2wT; sa.obs2b = obs2b; sa.npo = npo;
  sa.w1pT = w1pT; sa.img1b = img1b; sa.action = action;
  sa.bar = bar;
  scan64<<<192, 256, 0, stream>>>(sa);

  // batched prior: h_img = elu(deter_all @ img2_w + img2_b), then img3 head
  gemm64<2><<<dim3(10, 192), 256, 0, stream>>>(dall, 640, i2wb, 600, img2b,
                                               himg, 640, 640, 600, 640);
  head_prior<<<192, 256, 0, stream>>>(himg, i3wb, img3b, npr, out);
}